// Round 1
// baseline (1083.112 us; speedup 1.0000x reference)
//
#include <hip/hip_runtime.h>
#include <stdint.h>

typedef short bf16x8 __attribute__((ext_vector_type(8)));
typedef float f32x4 __attribute__((ext_vector_type(4)));

#define LOGITS_SZ 33505280u          // 128*128*2045
#define YT_SZ     261760u            // 128*2045
#define ACC_OFF   33767040u          // LOGITS_SZ + YT_SZ
#define PRED_ELEMS 67108864ull      // 1024*128*512 (per step)
#define TEMP_INV  (1.0f/0.07f)

// workspace layout (ushort units)
#define WBF_OFF   0ull
#define PRED_OFF  524288ull                     // after wbf (2*512*512)
#define CTMP_OFF  (PRED_OFF + 2*PRED_ELEMS)     // 134742016
#define PBF_OFF   (CTMP_OFF + 33554432ull)      // big path only
#define TBF_OFF   (PBF_OFF + 67108864ull)
#define BIG_USH   (TBF_OFF + 67108864ull)       // 302514176 ush = 605 MB

__device__ inline ushort f2bf(float f) {
  uint32_t u = __float_as_uint(f);
  u = (u + 0x7fffu + ((u >> 16) & 1u)) >> 16;
  return (ushort)u;
}
__device__ inline float bf2f(ushort h) { return __uint_as_float(((uint32_t)h) << 16); }
__device__ inline uint32_t pack2(float a, float b) {
  return (uint32_t)f2bf(a) | ((uint32_t)f2bf(b) << 16);
}
__device__ inline void gl_lds16(const ushort* g, ushort* l) {
  __builtin_amdgcn_global_load_lds(
      (const __attribute__((address_space(1))) uint32_t*)g,
      (__attribute__((address_space(3))) uint32_t*)l, 16, 0, 0);
}

// ---------------- misc init ----------------
__global__ void init_misc(float* __restrict__ out) {
  uint32_t i = blockIdx.x * 256u + threadIdx.x;
  if (i < YT_SZ) out[LOGITS_SZ + i] = (float)(i / 2045u);
  if (i < 2u) out[ACC_OFF + i] = 0.0f;
}

__global__ void cast_w(const float* __restrict__ w1, const float* __restrict__ w2,
                       ushort* __restrict__ wbf) {
  uint32_t i = blockIdx.x * 256u + threadIdx.x;
  float v = (i < 262144u) ? w1[i] : w2[i - 262144u];
  wbf[i] = f2bf(v);
}

// big-path: cast patient, tsteps, W to bf16 (8 floats / thread)
__global__ void cast_all(const float* __restrict__ p, const float* __restrict__ t,
                         const float* __restrict__ w1, const float* __restrict__ w2,
                         ushort* __restrict__ pbf, ushort* __restrict__ tbf,
                         ushort* __restrict__ wbf) {
  size_t c = (size_t)blockIdx.x * 256u + threadIdx.x;
  const float* src; ushort* dst; size_t off;
  if (c < 8388608ull)            { src = p;  dst = pbf; off = c * 8; }
  else if (c < 16777216ull)      { src = t;  dst = tbf; off = (c - 8388608ull) * 8; }
  else {
    size_t cc = c - 16777216ull; // < 65536
    if (cc < 32768ull) { src = w1; dst = wbf;          off = cc * 8; }
    else               { src = w2; dst = wbf + 262144; off = (cc - 32768ull) * 8; }
  }
  float4 f0 = *(const float4*)(src + off), f1 = *(const float4*)(src + off + 4);
  uint4 v = make_uint4(pack2(f0.x, f0.y), pack2(f0.z, f0.w),
                       pack2(f1.x, f1.y), pack2(f1.z, f1.w));
  *(uint4*)(dst + off) = v;
}

// ---------------- unified 128x128x512 GEMM ----------------
// PRED: out pred[s][l][m][c] = patient[m][l][:].W_s[c][:] + b_s[c]
// !PRED (logit): out ctmp[s][l][n][m] = t[n][l+s+1][:].pred[s][l][m][:]
// ABF: A staged bf16 via global_load_lds; else fp32 VALU-convert (swizzled LDS)
template<bool PRED, bool ABF>
__global__ __launch_bounds__(256, 3)
void gemm_kernel(const float* __restrict__ af32, const ushort* __restrict__ abf,
                 const ushort* __restrict__ bmat, const float* __restrict__ b1,
                 const float* __restrict__ b2, ushort* __restrict__ outp)
{
  __shared__ __align__(16) ushort As[128 * 32];
  __shared__ __align__(16) ushort Bs[128 * 32];
  __shared__ __align__(16) ushort Sb[128 * 128];

  const int t = threadIdx.x;
  const int lane = t & 63, w = t >> 6;
  const int q = lane >> 4, c16 = lane & 15;
  const int wr = (w & 1) * 64, wc = (w >> 1) * 64;

  size_t a_off, a_stride, ostride;
  const ushort* bbase; ushort* obase;
  const float* bias = nullptr;

  if (PRED) {
    // xcd-swizzled: all 8 (s,ct) of a row band on one XCD, consecutive
    int id = blockIdx.x;               // 8192
    int x = id & 7, p = id >> 3;
    int y = x + 8 * (p >> 3);          // row band 0..1023
    int sct = p & 7, s = sct >> 2, ct = sct & 3;
    int r0 = y * 128, m = y >> 3, l0 = (y & 7) * 128;
    a_off = (size_t)r0 * 512; a_stride = 512;
    bbase = bmat + (size_t)s * 262144 + (size_t)ct * 128 * 512;
    obase = outp + (size_t)s * PRED_ELEMS + ((size_t)l0 * 128 + m) * 512 + ct * 128;
    ostride = 65536;
    bias = (s ? b2 : b1) + ct * 128;
  } else {
    // pair (s01=0,l=g) & (s01=1,l=g-1) share t-column g+1, same XCD
    int id = blockIdx.x;               // 2048
    int x = id & 7, p = id >> 3;
    int g = x + 8 * (p >> 1), s01 = p & 1;
    int l = g - s01;
    if (l < 0 || l > (s01 ? 1021 : 1022)) return;
    int lc = g + 1;
    a_off = (size_t)lc * 512; a_stride = 524288;   // t rows n stride
    bbase = bmat + (size_t)s01 * PRED_ELEMS + (size_t)l * 65536;
    obase = outp + ((size_t)s01 * 1024 + l) * 16384;
    ostride = 128;
  }

  f32x4 acc[4][4] = {};

  const int ar = t >> 1, ah = t & 1;
  const float* asrcf = ABF ? nullptr : (af32 + a_off + (size_t)ar * a_stride + ah * 16);
  const int fr = (ar >> 1) & 3;
  const int drow = lane >> 2;            // dma: 4 lanes x 16B per row
  const int dcol = (lane & 3) * 8;

  for (int kk = 0; kk < 16; ++kk) {
    const int p0 = kk * 32;
    if (ABF) {
      const ushort* ab = abf + a_off + p0 + dcol;
      gl_lds16(ab + (size_t)(w * 16 + drow) * a_stride,      &As[w * 512]);
      gl_lds16(ab + (size_t)(64 + w * 16 + drow) * a_stride, &As[2048 + w * 512]);
    } else {
      const float4* af = (const float4*)(asrcf + p0);
      float4 f0 = af[0], f1 = af[1], f2 = af[2], f3 = af[3];
      uint4 v0 = make_uint4(pack2(f0.x, f0.y), pack2(f0.z, f0.w), pack2(f1.x, f1.y), pack2(f1.z, f1.w));
      uint4 v1 = make_uint4(pack2(f2.x, f2.y), pack2(f2.z, f2.w), pack2(f3.x, f3.y), pack2(f3.z, f3.w));
      *(uint4*)&As[ar * 32 + (((2 * ah)     ^ fr) << 3)] = v0;
      *(uint4*)&As[ar * 32 + (((2 * ah + 1) ^ fr) << 3)] = v1;
    }
    {
      const ushort* bb = bbase + p0 + dcol;
      gl_lds16(bb + (size_t)(w * 16 + drow) * 512,      &Bs[w * 512]);
      gl_lds16(bb + (size_t)(64 + w * 16 + drow) * 512, &Bs[2048 + w * 512]);
    }
    __syncthreads();
    bf16x8 a[4], b[4];
#pragma unroll
    for (int i = 0; i < 4; ++i) {
      int row = wr + i * 16 + c16;
      a[i] = ABF ? *(const bf16x8*)&As[row * 32 + q * 8]
                 : *(const bf16x8*)&As[row * 32 + ((q ^ ((row >> 1) & 3)) << 3)];
      int col = wc + i * 16 + c16;
      b[i] = *(const bf16x8*)&Bs[col * 32 + q * 8];
    }
#pragma unroll
    for (int i = 0; i < 4; ++i)
#pragma unroll
      for (int j = 0; j < 4; ++j)
        acc[i][j] = __builtin_amdgcn_mfma_f32_16x16x32_bf16(a[i], b[j], acc[i][j], 0, 0, 0);
    __syncthreads();
  }

  // epilogue: LDS transpose -> coalesced 16B stores
#pragma unroll
  for (int j = 0; j < 4; ++j) {
    int col = wc + j * 16 + c16;
    float bj = PRED ? bias[col] : 0.0f;
#pragma unroll
    for (int i = 0; i < 4; ++i)
#pragma unroll
      for (int rr = 0; rr < 4; ++rr) {
        int row = wr + i * 16 + q * 4 + rr;
        Sb[row * 128 + col] = f2bf(acc[i][j][rr] + bj);
      }
  }
  __syncthreads();
#pragma unroll
  for (int it = 0; it < 8; ++it) {
    int idx = it * 256 + t;
    int row = idx >> 4, c8 = (idx & 15) * 8;
    *(uint4*)(obase + (size_t)row * ostride + c8) = *(const uint4*)&Sb[row * 128 + c8];
  }
}

// ---------------- transpose: out[n][m][lcat] = Ctmp[s][l][n][m] / T ----------------
__global__ void transpose_kernel(const ushort* __restrict__ ctmp, float* __restrict__ out)
{
  const int nmt = blockIdx.x, lt = blockIdx.y, s01 = blockIdx.z;
  const int Ls = s01 ? 1022 : 1023;
  const int lbase = s01 ? 1023 : 0;
  const int t = threadIdx.x;
  __shared__ float T[64][65];
  {
    int i = t >> 2, j0 = (t & 3) * 16;
    const ushort* src = ctmp + ((size_t)(s01 * 1024 + lt * 64 + i)) * 16384 + nmt * 64 + j0;
    uint4 v0 = *(const uint4*)src;
    uint4 v1 = *(const uint4*)(src + 8);
    float* dst = &T[i][j0];
    uint32_t wsv[8] = {v0.x, v0.y, v0.z, v0.w, v1.x, v1.y, v1.z, v1.w};
#pragma unroll
    for (int e = 0; e < 8; ++e) {
      dst[2 * e]     = bf2f((ushort)(wsv[e] & 0xffffu));
      dst[2 * e + 1] = bf2f((ushort)(wsv[e] >> 16));
    }
  }
  __syncthreads();
  {
    int nm = t >> 2, l0 = (t & 3) * 16;
    size_t obase = (size_t)(nmt * 64 + nm) * 2045 + lbase + lt * 64 + l0;
#pragma unroll
    for (int k = 0; k < 16; ++k) {
      int lg = lt * 64 + l0 + k;
      if (lg < Ls) out[obase + k] = T[l0 + k][nm] * TEMP_INV;
    }
  }
}

// ---------------- accuracy ----------------
__global__ void acc_kernel(const ushort* __restrict__ ctmp, float* __restrict__ accbuf)
{
  const int idx = blockIdx.x;
  const int s01 = idx & 1;
  const int l = idx >> 1;
  const int t = threadIdx.x;
  const ushort* base = ctmp + ((size_t)s01 * 1024 + (size_t)l) * 16384;
  const int n = t >> 1, half = t & 1;
  const ushort* row = base + n * 128 + half * 64;
  float mx = -1e30f;
#pragma unroll
  for (int k8 = 0; k8 < 8; ++k8) {
    uint4 v = *(const uint4*)(row + k8 * 8);
    uint32_t wsv[4] = {v.x, v.y, v.z, v.w};
#pragma unroll
    for (int e = 0; e < 4; ++e) {
      int m0 = half * 64 + k8 * 8 + e * 2;
      float a0 = bf2f((ushort)(wsv[e] & 0xffffu));
      float a1 = bf2f((ushort)(wsv[e] >> 16));
      if (m0 != n)     mx = fmaxf(mx, a0);
      if (m0 + 1 != n) mx = fmaxf(mx, a1);
    }
  }
  float pos = bf2f(base[n * 128 + n]);
  mx = fmaxf(mx, __shfl_xor(mx, 1, 64));
  int ok = (half == 0 && pos > mx) ? 1 : 0;
  for (int off = 32; off > 0; off >>= 1) ok += __shfl_down(ok, off, 64);
  __shared__ int partial[4];
  if ((t & 63) == 0) partial[t >> 6] = ok;
  __syncthreads();
  if (t == 0) {
    int sum = partial[0] + partial[1] + partial[2] + partial[3];
    atomicAdd(&accbuf[s01], (float)sum);
  }
}

__global__ void scale_kernel(float* accbuf) {
  if (threadIdx.x == 0) accbuf[0] *= (1.0f / 130944.0f);
  if (threadIdx.x == 1) accbuf[1] *= (1.0f / 130816.0f);
}

extern "C" void kernel_launch(void* const* d_in, const int* in_sizes, int n_in,
                              void* d_out, int out_size, void* d_ws, size_t ws_size,
                              hipStream_t stream)
{
  const float* tsteps  = (const float*)d_in[0];
  const float* patient = (const float*)d_in[1];
  const float* W1 = (const float*)d_in[2];
  const float* b1 = (const float*)d_in[3];
  const float* W2 = (const float*)d_in[4];
  const float* b2 = (const float*)d_in[5];
  float* out = (float*)d_out;
  ushort* wsp  = (ushort*)d_ws;
  ushort* wbf  = wsp + WBF_OFF;
  ushort* pred = wsp + PRED_OFF;
  ushort* ctmp = wsp + CTMP_OFF;

  const bool big = ws_size >= BIG_USH * 2ull;  // 605 MB needed for bf16 pre-cast path

  init_misc<<<1023, 256, 0, stream>>>(out);
  if (big) {
    ushort* pbf = wsp + PBF_OFF;
    ushort* tbf = wsp + TBF_OFF;
    cast_all<<<65792, 256, 0, stream>>>(patient, tsteps, W1, W2, pbf, tbf, wbf);
    gemm_kernel<true, true><<<8192, 256, 0, stream>>>(nullptr, pbf, wbf, b1, b2, pred);
    gemm_kernel<false, true><<<2048, 256, 0, stream>>>(nullptr, tbf, pred, nullptr, nullptr, ctmp);
  } else {
    cast_w<<<2048, 256, 0, stream>>>(W1, W2, wbf);
    gemm_kernel<true, false><<<8192, 256, 0, stream>>>(patient, nullptr, wbf, b1, b2, pred);
    gemm_kernel<false, false><<<2048, 256, 0, stream>>>(tsteps, nullptr, pred, nullptr, nullptr, ctmp);
  }
  transpose_kernel<<<dim3(256, 16, 2), 256, 0, stream>>>(ctmp, out);
  acc_kernel<<<2045, 256, 0, stream>>>(ctmp, out + ACC_OFF);
  scale_kernel<<<1, 64, 0, stream>>>(out + ACC_OFF);
}

// Round 2
// 917.004 us; speedup vs baseline: 1.1811x; 1.1811x over previous
//
#include <hip/hip_runtime.h>
#include <stdint.h>

typedef short bf16x8 __attribute__((ext_vector_type(8)));
typedef float f32x4 __attribute__((ext_vector_type(4)));

#define LOGITS_SZ 33505280u          // 128*128*2045
#define YT_SZ     261760u            // 128*2045
#define ACC_OFF   33767040u          // LOGITS_SZ + YT_SZ
#define TEMP_INV  (1.0f/0.07f)

// workspace layout (ushort units) — no pred intermediate anymore
#define WBF_OFF   0ull
#define CTMP_OFF  524288ull                     // after wbf (2*512*512)
#define PBF_OFF   (CTMP_OFF + 33554432ull)      // ctmp 2*1024*128*128
#define TBF_OFF   (PBF_OFF + 67108864ull)
// total = TBF_OFF + 67108864 = 168296448 ush = 337 MB (prev path needed 605 MB, ws confirmed >= that)

__device__ inline ushort f2bf(float f) {
  uint32_t u = __float_as_uint(f);
  u = (u + 0x7fffu + ((u >> 16) & 1u)) >> 16;
  return (ushort)u;
}
__device__ inline float bf2f(ushort h) { return __uint_as_float(((uint32_t)h) << 16); }
__device__ inline uint32_t pack2(float a, float b) {
  return (uint32_t)f2bf(a) | ((uint32_t)f2bf(b) << 16);
}
__device__ inline void gl_lds16(const ushort* g, ushort* l) {
  __builtin_amdgcn_global_load_lds(
      (const __attribute__((address_space(1))) uint32_t*)g,
      (__attribute__((address_space(3))) uint32_t*)l, 16, 0, 0);
}

// ---------------- misc init ----------------
__global__ void init_misc(float* __restrict__ out) {
  uint32_t i = blockIdx.x * 256u + threadIdx.x;
  if (i < YT_SZ) out[LOGITS_SZ + i] = (float)(i / 2045u);
  if (i < 2u) out[ACC_OFF + i] = 0.0f;
}

// cast patient, tsteps (TRANSPOSED to [l][m][p]), W (as [c][p]) to bf16
__global__ void cast_all(const float* __restrict__ p, const float* __restrict__ t,
                         const float* __restrict__ w1, const float* __restrict__ w2,
                         ushort* __restrict__ pbf, ushort* __restrict__ tbf,
                         ushort* __restrict__ wbf) {
  size_t c = (size_t)blockIdx.x * 256u + threadIdx.x;
  const float* src; ushort* dst; size_t soff, doff;
  if (c < 16777216ull) {
    size_t cc = c;
    if (cc < 8388608ull) { src = p; dst = pbf; }
    else                 { src = t; dst = tbf; cc -= 8388608ull; }
    // src flat index: (m*1024 + l)*512 + pb*8  ->  dst: (l*128 + m)*512 + pb*8
    size_t pb = cc & 63, l = (cc >> 6) & 1023, m = cc >> 16;
    soff = cc * 8;
    doff = ((l << 7) + m) * 512 + pb * 8;
  } else {
    size_t cc = c - 16777216ull; // < 65536
    if (cc < 32768ull) { src = w1; dst = wbf; }
    else               { src = w2; dst = wbf + 262144; cc -= 32768ull; }
    soff = cc * 8; doff = soff;
  }
  float4 f0 = *(const float4*)(src + soff), f1 = *(const float4*)(src + soff + 4);
  uint4 v = make_uint4(pack2(f0.x, f0.y), pack2(f0.z, f0.w),
                       pack2(f1.x, f1.y), pack2(f1.z, f1.w));
  *(uint4*)(dst + doff) = v;
}

// ---------------- fused PRED+logit kernel ----------------
// per block (s01, l):
//   loop ct=0..3 over 128-wide c-subtiles:
//     phase1: P_sub[m][cc] = patient[l-col] . W_s[ct] + b  -> Ps (LDS, XOR-swizzled bf16)
//     phase2: acc2[n][m]  += t[lc-col][ct chunk] . P_sub^T  (B straight from LDS)
//   epilogue: ctmp[s][l][n][m] = bf16(acc2)
__global__ __launch_bounds__(256, 2)
void fused_kernel(const ushort* __restrict__ pbf, const ushort* __restrict__ tbf,
                  const ushort* __restrict__ wbf, const float* __restrict__ b1,
                  const float* __restrict__ b2, ushort* __restrict__ ctmp)
{
  __shared__ __align__(16) ushort As[128 * 32];   // 8 KB staging (patient / t chunks)
  __shared__ __align__(16) ushort Bs[128 * 32];   // 8 KB staging (W chunks)
  __shared__ __align__(16) ushort Ps[128 * 128];  // 32 KB P subtile / epilogue buffer

  const int t = threadIdx.x;
  const int lane = t & 63, w = t >> 6;
  const int q = lane >> 4, c16 = lane & 15;
  const int wr = (w & 1) * 64, wc = (w >> 1) * 64;

  // pairing: (s01=0,l=g) & (s01=1,l=g-1) share t-column g+1, same XCD
  int id = blockIdx.x;                 // 2048
  int x = id & 7, pp = id >> 3;
  int g = x + 8 * (pp >> 1), s01 = pp & 1;
  int l = g - s01;
  if (l < 0 || l > (s01 ? 1021 : 1022)) return;
  int lc = g + 1;                      // = l + step

  const ushort* abase = pbf + (size_t)l * 65536;    // patient rows m, stride 512, contiguous
  const ushort* tbase = tbf + (size_t)lc * 65536;   // t rows n, stride 512, contiguous
  const ushort* wbase = wbf + (size_t)s01 * 262144; // W_s rows c, stride 512
  const float* bias = s01 ? b2 : b1;
  ushort* obase = ctmp + ((size_t)s01 * 1024 + (size_t)l) * 16384;

  const int drow = lane >> 2;            // dma: 4 lanes x 16B per row
  const int dcol = (lane & 3) * 8;

  f32x4 acc2[4][4] = {};

  for (int ct = 0; ct < 4; ++ct) {
    // ---- phase 1: P_sub = patient_l . W_s[ct*128 .. +128] ----
    f32x4 acc1[4][4] = {};
    const ushort* wct = wbase + (size_t)ct * 65536;   // ct*128 rows of 512
    for (int kk = 0; kk < 16; ++kk) {
      const int p0 = kk * 32;
      { const ushort* ab = abase + p0 + dcol;
        gl_lds16(ab + (size_t)(w * 16 + drow) * 512,      &As[w * 512]);
        gl_lds16(ab + (size_t)(64 + w * 16 + drow) * 512, &As[2048 + w * 512]); }
      { const ushort* bb = wct + p0 + dcol;
        gl_lds16(bb + (size_t)(w * 16 + drow) * 512,      &Bs[w * 512]);
        gl_lds16(bb + (size_t)(64 + w * 16 + drow) * 512, &Bs[2048 + w * 512]); }
      __syncthreads();
      bf16x8 a[4], b[4];
#pragma unroll
      for (int i = 0; i < 4; ++i) {
        a[i] = *(const bf16x8*)&As[(wr + i * 16 + c16) * 32 + q * 8];
        b[i] = *(const bf16x8*)&Bs[(wc + i * 16 + c16) * 32 + q * 8];
      }
#pragma unroll
      for (int i = 0; i < 4; ++i)
#pragma unroll
        for (int j = 0; j < 4; ++j)
          acc1[i][j] = __builtin_amdgcn_mfma_f32_16x16x32_bf16(a[i], b[j], acc1[i][j], 0, 0, 0);
      __syncthreads();
    }
    // write P_sub (+bias) to Ps, XOR-swizzled along cc to kill phase-2 read conflicts
#pragma unroll
    for (int j = 0; j < 4; ++j) {
      int col = wc + j * 16 + c16;
      float bj = bias[ct * 128 + col];
#pragma unroll
      for (int i = 0; i < 4; ++i)
#pragma unroll
        for (int rr = 0; rr < 4; ++rr) {
          int row = wr + i * 16 + q * 4 + rr;            // m
          Ps[row * 128 + (col ^ ((row & 7) << 3))] = f2bf(acc1[i][j][rr] + bj);
        }
    }
    // pre-stage t chunk for kk2=0 (As free: last phase-1 barrier passed)
    { const ushort* ab = tbase + ct * 128 + dcol;
      gl_lds16(ab + (size_t)(w * 16 + drow) * 512,      &As[w * 512]);
      gl_lds16(ab + (size_t)(64 + w * 16 + drow) * 512, &As[2048 + w * 512]); }
    __syncthreads();   // covers Ps writes + t dma
    // ---- phase 2: acc2 += t_chunk . P_sub^T ----
#pragma unroll
    for (int kk2 = 0; kk2 < 4; ++kk2) {
      bf16x8 a[4], b[4];
#pragma unroll
      for (int i = 0; i < 4; ++i) {
        a[i] = *(const bf16x8*)&As[(wr + i * 16 + c16) * 32 + q * 8];
        int col = wc + i * 16 + c16;                     // m
        b[i] = *(const bf16x8*)&Ps[col * 128 + ((kk2 * 32 + q * 8) ^ ((col & 7) << 3))];
      }
#pragma unroll
      for (int i = 0; i < 4; ++i)
#pragma unroll
        for (int j = 0; j < 4; ++j)
          acc2[i][j] = __builtin_amdgcn_mfma_f32_16x16x32_bf16(a[i], b[j], acc2[i][j], 0, 0, 0);
      __syncthreads();
      if (kk2 < 3) {
        const ushort* ab = tbase + ct * 128 + (kk2 + 1) * 32 + dcol;
        gl_lds16(ab + (size_t)(w * 16 + drow) * 512,      &As[w * 512]);
        gl_lds16(ab + (size_t)(64 + w * 16 + drow) * 512, &As[2048 + w * 512]);
        __syncthreads();
      }
    }
  }

  // ---- epilogue: acc2 -> Ps (plain) -> coalesced 16B stores ----
#pragma unroll
  for (int j = 0; j < 4; ++j) {
    int col = wc + j * 16 + c16;
#pragma unroll
    for (int i = 0; i < 4; ++i)
#pragma unroll
      for (int rr = 0; rr < 4; ++rr) {
        int row = wr + i * 16 + q * 4 + rr;              // n
        Ps[row * 128 + col] = f2bf(acc2[i][j][rr]);
      }
  }
  __syncthreads();
#pragma unroll
  for (int it = 0; it < 8; ++it) {
    int idx = it * 256 + t;
    int row = idx >> 4, c8 = (idx & 15) * 8;
    *(uint4*)(obase + (size_t)row * 128 + c8) = *(const uint4*)&Ps[row * 128 + c8];
  }
}

// ---------------- transpose: out[n][m][lcat] = Ctmp[s][l][n][m] / T ----------------
__global__ void transpose_kernel(const ushort* __restrict__ ctmp, float* __restrict__ out)
{
  const int nmt = blockIdx.x, lt = blockIdx.y, s01 = blockIdx.z;
  const int Ls = s01 ? 1022 : 1023;
  const int lbase = s01 ? 1023 : 0;
  const int t = threadIdx.x;
  __shared__ float T[64][65];
  {
    int i = t >> 2, j0 = (t & 3) * 16;
    const ushort* src = ctmp + ((size_t)(s01 * 1024 + lt * 64 + i)) * 16384 + nmt * 64 + j0;
    uint4 v0 = *(const uint4*)src;
    uint4 v1 = *(const uint4*)(src + 8);
    float* dst = &T[i][j0];
    uint32_t wsv[8] = {v0.x, v0.y, v0.z, v0.w, v1.x, v1.y, v1.z, v1.w};
#pragma unroll
    for (int e = 0; e < 8; ++e) {
      dst[2 * e]     = bf2f((ushort)(wsv[e] & 0xffffu));
      dst[2 * e + 1] = bf2f((ushort)(wsv[e] >> 16));
    }
  }
  __syncthreads();
  {
    // lane-major over l: fully coalesced scalar stores
    int ll = t & 63, nm0 = t >> 6;
    int lg = lt * 64 + ll;
    if (lg < Ls) {
      size_t ob = (size_t)lbase + lg;
#pragma unroll
      for (int pass = 0; pass < 16; ++pass) {
        int nm = pass * 4 + nm0;
        out[(size_t)(nmt * 64 + nm) * 2045 + ob] = T[ll][nm] * TEMP_INV;
      }
    }
  }
}

// ---------------- accuracy ----------------
__global__ void acc_kernel(const ushort* __restrict__ ctmp, float* __restrict__ accbuf)
{
  const int idx = blockIdx.x;
  const int s01 = idx & 1;
  const int l = idx >> 1;
  const int t = threadIdx.x;
  const ushort* base = ctmp + ((size_t)s01 * 1024 + (size_t)l) * 16384;
  const int n = t >> 1, half = t & 1;
  const ushort* row = base + n * 128 + half * 64;
  float mx = -1e30f;
#pragma unroll
  for (int k8 = 0; k8 < 8; ++k8) {
    uint4 v = *(const uint4*)(row + k8 * 8);
    uint32_t wsv[4] = {v.x, v.y, v.z, v.w};
#pragma unroll
    for (int e = 0; e < 4; ++e) {
      int m0 = half * 64 + k8 * 8 + e * 2;
      float a0 = bf2f((ushort)(wsv[e] & 0xffffu));
      float a1 = bf2f((ushort)(wsv[e] >> 16));
      if (m0 != n)     mx = fmaxf(mx, a0);
      if (m0 + 1 != n) mx = fmaxf(mx, a1);
    }
  }
  float pos = bf2f(base[n * 128 + n]);
  mx = fmaxf(mx, __shfl_xor(mx, 1, 64));
  int ok = (half == 0 && pos > mx) ? 1 : 0;
  for (int off = 32; off > 0; off >>= 1) ok += __shfl_down(ok, off, 64);
  __shared__ int partial[4];
  if ((t & 63) == 0) partial[t >> 6] = ok;
  __syncthreads();
  if (t == 0) {
    int sum = partial[0] + partial[1] + partial[2] + partial[3];
    atomicAdd(&accbuf[s01], (float)sum);
  }
}

__global__ void scale_kernel(float* accbuf) {
  if (threadIdx.x == 0) accbuf[0] *= (1.0f / 130944.0f);
  if (threadIdx.x == 1) accbuf[1] *= (1.0f / 130816.0f);
}

extern "C" void kernel_launch(void* const* d_in, const int* in_sizes, int n_in,
                              void* d_out, int out_size, void* d_ws, size_t ws_size,
                              hipStream_t stream)
{
  const float* tsteps  = (const float*)d_in[0];
  const float* patient = (const float*)d_in[1];
  const float* W1 = (const float*)d_in[2];
  const float* b1 = (const float*)d_in[3];
  const float* W2 = (const float*)d_in[4];
  const float* b2 = (const float*)d_in[5];
  float* out = (float*)d_out;
  ushort* wsp  = (ushort*)d_ws;
  ushort* wbf  = wsp + WBF_OFF;
  ushort* ctmp = wsp + CTMP_OFF;
  ushort* pbf  = wsp + PBF_OFF;
  ushort* tbf  = wsp + TBF_OFF;

  init_misc<<<1023, 256, 0, stream>>>(out);
  cast_all<<<65792, 256, 0, stream>>>(patient, tsteps, W1, W2, pbf, tbf, wbf);
  fused_kernel<<<2048, 256, 0, stream>>>(pbf, tbf, wbf, b1, b2, ctmp);
  transpose_kernel<<<dim3(256, 16, 2), 256, 0, stream>>>(ctmp, out);
  acc_kernel<<<2045, 256, 0, stream>>>(ctmp, out + ACC_OFF);
  scale_kernel<<<1, 64, 0, stream>>>(out + ACC_OFF);
}